// Round 1
// baseline (32139.206 us; speedup 1.0000x reference)
//
#include <hip/hip_runtime.h>

// LSTMx: 2-layer LSTM, L=512, N=64, IN=256, H=1024. fp32 in/out, bf16 MFMA compute.
// Structure: 3 prep kernels (pack weights/x to bf16, combine biases, init h, zero barrier)
// + one persistent kernel (256 blocks = 1/CU guaranteed by 137KB LDS) doing the
// layer-pipelined recurrence with a hand-rolled two-level grid barrier.

typedef unsigned short u16;
typedef __attribute__((ext_vector_type(8))) short short8;
typedef __attribute__((ext_vector_type(4))) float float4v;
typedef __attribute__((ext_vector_type(4))) int int4v;

// ---- workspace layout (bytes) ----
#define WP0_OFF   0u               // 128*32*1280*2 = 10485760  (layer0 packed W, bf16)
#define WP1_OFF   10485760u        // 128*32*2048*2 = 16777216  (layer1 packed W)
#define XB_OFF    27262976u        // 512*64*256*2  = 16777216  (x in bf16)
#define HB0_OFF   44040192u        // 2*64*1024*2   = 262144    (h0 double buffer, bf16)
#define HB1_OFF   44302336u        // 2*64*1024*2
#define BC0_OFF   44564480u        // 4096*4  (b_ih0+b_hh0)
#define BC1_OFF   44580864u        // 4096*4
#define BAR_OFF   44597248u        // 1024*4  (grid barrier state)

// ---- output offsets (floats) ----
#define OUT_Y_OFF 0
#define ALLC_OFF  33554432
#define HN_OFF    100663296
#define CN_OFF    100794368

// LDS: W slice (max 32 rows * (2048+8) * 2B = 131584) + gate scratch 64*33*4 = 8448
#define SC_BYTE_OFF 131584
#define LDS_BYTES   140032

__device__ inline u16 f2b(float v) {  // fp32 -> bf16 RTNE (finite inputs)
  union { float f; unsigned u; } a; a.f = v;
  unsigned r = a.u + 0x7FFFu + ((a.u >> 16) & 1u);
  return (u16)(r >> 16);
}

__device__ inline float sigf(float x) { return 1.0f / (1.0f + __expf(-x)); }
__device__ inline float tanh_fast(float x) { return 1.0f - 2.0f / (1.0f + __expf(2.0f * x)); }

// ---------------- prep kernels ----------------

// Pack [w_ih0 | w_hh0] rows into per-block contiguous bf16 slices.
// Block b owns h-cols j in [b*8, b*8+8); packed row q = g*8+jj -> global row g*1024 + b*8 + jj.
__global__ void pack_w0(const float* __restrict__ w_ih, const float* __restrict__ w_hh,
                        u16* __restrict__ wp) {
  int k = blockIdx.x * 256 + threadIdx.x;   // 0..1279
  int q = blockIdx.y;                       // 0..31
  int b = blockIdx.z;                       // 0..127
  int g = q >> 3, jj = q & 7;
  int r = g * 1024 + b * 8 + jj;
  float v = (k < 256) ? w_ih[r * 256 + k] : w_hh[r * 1024 + (k - 256)];
  wp[(b * 32 + q) * 1280 + k] = f2b(v);
}

__global__ void pack_w1(const float* __restrict__ w_ih, const float* __restrict__ w_hh,
                        u16* __restrict__ wp) {
  int k = blockIdx.x * 256 + threadIdx.x;   // 0..2047
  int q = blockIdx.y;
  int b = blockIdx.z;
  int g = q >> 3, jj = q & 7;
  int r = g * 1024 + b * 8 + jj;
  float v = (k < 1024) ? w_ih[r * 1024 + k] : w_hh[r * 1024 + (k - 1024)];
  wp[(b * 32 + q) * 2048 + k] = f2b(v);
}

// x -> bf16, h0 -> bf16 buffers, combined biases, zero barrier state.
__global__ void prep_misc(const float* __restrict__ x, const float* __restrict__ h0,
                          const float* __restrict__ bih0, const float* __restrict__ bhh0,
                          const float* __restrict__ bih1, const float* __restrict__ bhh1,
                          u16* __restrict__ xb, u16* __restrict__ hb0, u16* __restrict__ hb1,
                          float* __restrict__ bc0, float* __restrict__ bc1,
                          unsigned* __restrict__ bar) {
  int i = blockIdx.x * 256 + threadIdx.x;
  if (i < 8388608) { xb[i] = f2b(x[i]); return; }
  i -= 8388608;
  if (i < 65536) { hb0[i] = f2b(h0[i]); return; }
  i -= 65536;
  if (i < 65536) { hb1[i] = f2b(h0[65536 + i]); return; }
  i -= 65536;
  if (i < 4096) { bc0[i] = bih0[i] + bhh0[i]; return; }
  i -= 4096;
  if (i < 4096) { bc1[i] = bih1[i] + bhh1[i]; return; }
  i -= 4096;
  if (i < 1024) bar[i] = 0u;
}

// ---------------- grid barrier (normal launch; co-residency forced by 137KB LDS) ----------------
// Two-level arrival (16 groups of 16) to avoid 256 serialized atomics on one line.
__device__ inline void grid_barrier(unsigned* __restrict__ bar, int gi) {
  __syncthreads();
  __threadfence();   // release: flush our h/output writes to agent scope
  if (threadIdx.x == 0) {
    unsigned* gen = bar + 576;  // own cacheline
    unsigned g = __hip_atomic_load(gen, __ATOMIC_RELAXED, __HIP_MEMORY_SCOPE_AGENT);
    unsigned a = __hip_atomic_fetch_add(bar + gi * 32, 1u, __ATOMIC_ACQ_REL, __HIP_MEMORY_SCOPE_AGENT);
    bool flipped = false;
    if (a == 15u) {
      __hip_atomic_store(bar + gi * 32, 0u, __ATOMIC_RELAXED, __HIP_MEMORY_SCOPE_AGENT);
      unsigned r = __hip_atomic_fetch_add(bar + 512, 1u, __ATOMIC_ACQ_REL, __HIP_MEMORY_SCOPE_AGENT);
      if (r == 15u) {
        __hip_atomic_store(bar + 512, 0u, __ATOMIC_RELAXED, __HIP_MEMORY_SCOPE_AGENT);
        __hip_atomic_store(gen, g + 1u, __ATOMIC_RELEASE, __HIP_MEMORY_SCOPE_AGENT);
        flipped = true;
      }
    }
    if (!flipped) {
      while (__hip_atomic_load(gen, __ATOMIC_RELAXED, __HIP_MEMORY_SCOPE_AGENT) == g)
        __builtin_amdgcn_s_sleep(2);
    }
  }
  __syncthreads();
  __threadfence();   // acquire: invalidate stale L1/L2 before reading new h
}

// ---------------- per-step GEMM K-loop ----------------
// Wave wv owns k-quarter [wv*KQ, (wv+1)*KQ) (units of 32), computes all 8 MFMA tiles
// (4 M-tiles x 2 N-tiles) -> 8 independent accumulator chains. A from global (3-deep
// register prefetch), B from LDS-resident W slice (read redundancy 1).
template<int KQ, int SW>
__device__ __attribute__((always_inline)) inline
void kloop(const u16* __restrict__ pA, const u16* __restrict__ pB,
           int4v offA, int4v offB, const u16* __restrict__ Wl,
           int brow0, int brow1, int wv, float4v acc[4][2]) {
  const int base = wv * KQ;
  short8 as[3][4];
#pragma unroll
  for (int p = 0; p < 3; ++p) {
    int gks = base + p;
#pragma unroll
    for (int mt = 0; mt < 4; ++mt) {
      const u16* ap = (gks < SW) ? (pA + offA[mt] + gks * 32)
                                 : (pB + offB[mt] + (gks - SW) * 32);
      as[p][mt] = *(const short8*)ap;
    }
  }
#pragma unroll
  for (int ks = 0; ks < KQ; ++ks) {
    const int gks = base + ks;
    short8 b0 = *(const short8*)&Wl[brow0 + gks * 32];
    short8 b1 = *(const short8*)&Wl[brow1 + gks * 32];
#pragma unroll
    for (int mt = 0; mt < 4; ++mt) {
      acc[mt][0] = __builtin_amdgcn_mfma_f32_16x16x32_bf16(as[ks % 3][mt], b0, acc[mt][0], 0, 0, 0);
      acc[mt][1] = __builtin_amdgcn_mfma_f32_16x16x32_bf16(as[ks % 3][mt], b1, acc[mt][1], 0, 0, 0);
    }
    if (ks + 3 < KQ) {
      const int gn = gks + 3;
#pragma unroll
      for (int mt = 0; mt < 4; ++mt) {
        const u16* ap = (gn < SW) ? (pA + offA[mt] + gn * 32)
                                  : (pB + offB[mt] + (gn - SW) * 32);
        as[ks % 3][mt] = *(const short8*)ap;
      }
    }
  }
}

// ---------------- persistent LSTM kernel ----------------
// Blocks 0..127: layer0 (K=1280: [x_t | h0]); blocks 128..255: layer1 (K=2048: [h0_t | h1]).
// Global step s: layer0 does t=s (s<512), layer1 does t=s-1 (s>=1). 513 steps, barrier each.
__global__ void __launch_bounds__(256, 1)
lstm_persist(const u16* __restrict__ wp0, const u16* __restrict__ wp1,
             const u16* __restrict__ xb, u16* __restrict__ hb0, u16* __restrict__ hb1,
             const float* __restrict__ bc0, const float* __restrict__ bc1,
             const float* __restrict__ c0in, float* __restrict__ out,
             unsigned* __restrict__ bar) {
  extern __shared__ char smem[];
  u16* Wl = (u16*)smem;
  float* sc = (float*)(smem + SC_BYTE_OFF);   // 64 x 33 fp32 gate scratch

  const int b = blockIdx.x;
  const int layer = b >> 7;
  const int blk = b & 127;
  const int tid = threadIdx.x;
  const int lane = tid & 63;
  const int wv = tid >> 6;
  const int l15 = lane & 15;
  const int qd = lane >> 4;
  const int qd8 = qd * 8;

  const int K = layer ? 2048 : 1280;
  const int KP = K + 8;                       // +16B pad per row -> 2-way (free) LDS conflicts
  const u16* wsrc = layer ? (wp1 + blk * 32 * 2048) : (wp0 + blk * 32 * 1280);

  // load W slice into LDS (one-time)
  for (int q = 0; q < 32; ++q) {
    int k = tid * 8;
    if (k < K) *(short8*)&Wl[q * KP + k] = *(const short8*)&wsrc[q * K + k];
  }
  __syncthreads();

  float* out_y = out + OUT_Y_OFF;
  float* all_c = out + ALLC_OFF;
  float* h_n   = out + HN_OFF;
  float* c_n   = out + CN_OFF;

  // elementwise assignment: lane handles (m0, jj) and (m0+8, jj)
  const int jj  = lane & 7;
  const int col = blk * 8 + jj;
  const float* bcl = layer ? bc1 : bc0;
  const float bi  = bcl[col];
  const float bff = bcl[1024 + col];
  const float bg  = bcl[2048 + col];
  const float bo  = bcl[3072 + col];
  const int m0 = wv * 16 + (lane >> 3);
  const int m1 = m0 + 8;
  float cst0 = c0in[layer * 65536 + m0 * 1024 + col];
  float cst1 = c0in[layer * 65536 + m1 * 1024 + col];

  int4v offA, offB;
#pragma unroll
  for (int mt = 0; mt < 4; ++mt) {
    int row = mt * 16 + l15;
    offA[mt] = layer ? (row * 1024 + qd8) : (row * 256 + qd8);
    offB[mt] = row * 1024 + qd8;
  }
  const int brow0 = l15 * KP + qd8;
  const int brow1 = (16 + l15) * KP + qd8;
  const int gi = b >> 4;

  for (int s = 0; s <= 512; ++s) {
    const bool act = layer ? (s >= 1) : (s < 512);
    const int t = layer ? (s - 1) : s;

    if (act) for (int i = tid; i < 2112; i += 256) sc[i] = 0.0f;
    __syncthreads();

    if (act) {
      const u16* pA; const u16* pB;
      if (layer == 0) { pA = xb + t * 16384;               pB = hb0 + (t & 1) * 65536; }
      else            { pA = hb0 + ((t + 1) & 1) * 65536;  pB = hb1 + (t & 1) * 65536; }

      float4v acc[4][2];
      float4v zz = {0.0f, 0.0f, 0.0f, 0.0f};
#pragma unroll
      for (int mt = 0; mt < 4; ++mt) { acc[mt][0] = zz; acc[mt][1] = zz; }

      if (layer == 0) kloop<10, 8>(pA, pB, offA, offB, Wl, brow0, brow1, wv, acc);
      else            kloop<16, 32>(pA, pB, offA, offB, Wl, brow0, brow1, wv, acc);

      // combine k-quarter partials: D[m][q], m = mt*16 + qd*4 + r, q = nt*16 + l15
#pragma unroll
      for (int mt = 0; mt < 4; ++mt)
#pragma unroll
        for (int nt = 0; nt < 2; ++nt)
#pragma unroll
          for (int r = 0; r < 4; ++r)
            atomicAdd(&sc[(mt * 16 + qd * 4 + r) * 33 + nt * 16 + l15], acc[mt][nt][r]);
    }
    __syncthreads();

    if (act) {
      u16* hnx = (layer ? hb1 : hb0) + ((t + 1) & 1) * 65536;
#pragma unroll
      for (int ee = 0; ee < 2; ++ee) {
        const int m = ee ? m1 : m0;
        float c_old = ee ? cst1 : cst0;
        float gI = sc[m * 33 + jj]      + bi;
        float gF = sc[m * 33 + 8 + jj]  + bff;
        float gG = sc[m * 33 + 16 + jj] + bg;
        float gO = sc[m * 33 + 24 + jj] + bo;
        float cn = sigf(gF) * c_old + sigf(gI) * tanh_fast(gG);
        float hn = sigf(gO) * tanh_fast(cn);
        if (ee) cst1 = cn; else cst0 = cn;
        hnx[m * 1024 + col] = f2b(hn);
        if (layer == 0) {
          __builtin_nontemporal_store(cn, &all_c[t * 131072 + m * 1024 + col]);
        } else {
          __builtin_nontemporal_store(cn, &all_c[t * 131072 + 65536 + m * 1024 + col]);
          __builtin_nontemporal_store(hn, &out_y[t * 65536 + m * 1024 + col]);
        }
        if (t == 511) {
          __builtin_nontemporal_store(hn, &h_n[layer * 65536 + m * 1024 + col]);
          __builtin_nontemporal_store(cn, &c_n[layer * 65536 + m * 1024 + col]);
        }
      }
    }
    grid_barrier(bar, gi);
  }
}

// ---------------- launch ----------------
extern "C" void kernel_launch(void* const* d_in, const int* in_sizes, int n_in,
                              void* d_out, int out_size, void* d_ws, size_t ws_size,
                              hipStream_t stream) {
  (void)in_sizes; (void)n_in; (void)out_size; (void)ws_size;
  const float* x     = (const float*)d_in[0];
  const float* h0i   = (const float*)d_in[1];
  const float* c0i   = (const float*)d_in[2];
  const float* w_ih0 = (const float*)d_in[3];
  const float* w_hh0 = (const float*)d_in[4];
  const float* b_ih0 = (const float*)d_in[5];
  const float* b_hh0 = (const float*)d_in[6];
  const float* w_ih1 = (const float*)d_in[7];
  const float* w_hh1 = (const float*)d_in[8];
  const float* b_ih1 = (const float*)d_in[9];
  const float* b_hh1 = (const float*)d_in[10];
  float* out = (float*)d_out;
  char* ws = (char*)d_ws;

  u16* wp0 = (u16*)(ws + WP0_OFF);
  u16* wp1 = (u16*)(ws + WP1_OFF);
  u16* xb  = (u16*)(ws + XB_OFF);
  u16* hb0 = (u16*)(ws + HB0_OFF);
  u16* hb1 = (u16*)(ws + HB1_OFF);
  float* bc0 = (float*)(ws + BC0_OFF);
  float* bc1 = (float*)(ws + BC1_OFF);
  unsigned* bar = (unsigned*)(ws + BAR_OFF);

  pack_w0<<<dim3(5, 32, 128), 256, 0, stream>>>(w_ih0, w_hh0, wp0);
  pack_w1<<<dim3(8, 32, 128), 256, 0, stream>>>(w_ih1, w_hh1, wp1);
  prep_misc<<<33316, 256, 0, stream>>>(x, h0i, b_ih0, b_hh0, b_ih1, b_hh1,
                                       xb, hb0, hb1, bc0, bc1, bar);

  hipFuncSetAttribute((const void*)lstm_persist,
                      hipFuncAttributeMaxDynamicSharedMemorySize, LDS_BYTES);
  lstm_persist<<<256, 256, LDS_BYTES, stream>>>(wp0, wp1, xb, hb0, hb1,
                                                bc0, bc1, c0i, out, bar);
}